// Round 20
// baseline (297.571 us; speedup 1.0000x reference)
//
#include <hip/hip_runtime.h>
#include <hip/hip_bf16.h>

// FraudSNN fused kernel: GEMM (bf16 MFMA) + LIF recurrence, T=10, F=256, H=512.
// R20: R19 (1-barrier/t, deferred LIF2, 178us) + 2-t fusion engineered to fit:
//  - per 2t-iter: 1 staging point, 1 barrier, 2 cp-passes (NOT R18's 4 passes)
//  - kk body per pass: 4 a-loads + 2 W1-loads + 8 MFMA (R19's ILP shape);
//    each W1 load feeds 4 MFMA (2rt x 2tl) -> W1 L2 traffic per CU 76us -> 38us
//  - LIF per (cp,rt): one mem1-plane RMW covers t and t+1 (halves LIF LDS traffic)
//  - barriers 10 -> 5 (+1 final); xt parity-dbuf (4 t-buffers), R19 safety proof
// Live ~95 regs < 120 budget; LDS 144.6 KB (mem1 64K + xt 67.6K + cur2 11.5K).

typedef short short8 __attribute__((ext_vector_type(8)));
typedef float f32x4 __attribute__((ext_vector_type(4)));

__device__ __forceinline__ unsigned short bfbits(float f) {
  union { __hip_bfloat16 h; unsigned short u; } c;
  c.h = __float2bfloat16(f);   // hardware RNE
  return c.u;
}

__device__ __forceinline__ unsigned int bfpack(float a, float b) {
  return (unsigned int)bfbits(a) | ((unsigned int)bfbits(b) << 16);
}

__device__ __forceinline__ float fast_sigmoid(float z) {
  float e = __expf(-z);
  return __builtin_amdgcn_rcpf(1.0f + e);
}

__device__ __forceinline__ void lif4(f32x4& mv, const f32x4 av, float w2c, float pr[4]) {
#pragma unroll
  for (int e = 0; e < 4; ++e) {
    float m   = fmaf(mv[e], 0.9f, av[e]);     // beta*mem + cur1
    float spk = fast_sigmoid(fmaf(m, 10.f, -10.f));
    mv[e] = m - spk;
    pr[e] = fmaf(spk, w2c, pr[e]);
  }
}

__global__ void w1_to_bf16(const float* __restrict__ w1, unsigned short* __restrict__ o) {
  int i = blockIdx.x * 256 + threadIdx.x;      // 32768 float4s
  float4 v = reinterpret_cast<const float4*>(w1)[i];
  reinterpret_cast<uint2*>(o)[i] = make_uint2(bfpack(v.x, v.y), bfpack(v.z, v.w));
}

__device__ __forceinline__ short8 cvt_frag(const float* p) {
  const float4 v0 = *reinterpret_cast<const float4*>(p);
  const float4 v1 = *reinterpret_cast<const float4*>(p + 4);
  union { unsigned int u[4]; short8 s; } cv;
  cv.u[0] = bfpack(v0.x, v0.y);
  cv.u[1] = bfpack(v0.z, v0.w);
  cv.u[2] = bfpack(v1.x, v1.y);
  cv.u[3] = bfpack(v1.z, v1.w);
  return cv.s;
}

// 512 threads = 8 waves. Block: 32 batch rows; wave w owns 32 rows x h in [w*64, w*64+64).
template <bool USE_WS>
__global__
__attribute__((amdgpu_flat_work_group_size(512, 512)))
void snn_main(const float* __restrict__ x,
              const unsigned short* __restrict__ w1bf,  // bf16 W1 (if USE_WS)
              const float* __restrict__ w1f,            // fp32 W1 (fallback)
              const float* __restrict__ b1,
              const float* __restrict__ w2,
              const float* __restrict__ b2,
              float* __restrict__ out)
{
  __shared__ __align__(16) float mem_lds[8][512][4];             // 65,536 B, 0-conflict slots
  __shared__ __align__(16) unsigned short xt[2][2][2][32][132];  // [par][tl][half][row][col] 67,584 B
  __shared__ float cur2_lds[10][32][9];                          // [t][row][wave] 11,520 B

  const int tid  = threadIdx.x;
  const int lane = tid & 63;
  const int wave = tid >> 6;          // 0..7
  const int l15  = lane & 15;
  const int lq   = lane >> 4;         // 0..3
  const long b0  = (long)blockIdx.x * 32;
  const int h0   = wave * 64;         // 4 col-tiles of 16

  float w2l[4], b1l[4];
#pragma unroll
  for (int ct = 0; ct < 4; ++ct) {
    int h = h0 + ct * 16 + l15;
    w2l[ct] = w2[h];
    b1l[ct] = b1[h];
  }

#pragma unroll
  for (int p = 0; p < 8; ++p) {
    f32x4 z = {0.f, 0.f, 0.f, 0.f};
    *reinterpret_cast<f32x4*>(&mem_lds[p][tid][0]) = z;
  }

  // staging: thread -> row sr (0..31), float4 col sc (0..15); 4 float4 per t
  const int sr = tid >> 4;
  const int sc = tid & 15;
  const float* xrow = x + (b0 + sr) * 2560;

  const unsigned short* wb = w1bf + (h0 + l15) * 256 + lq * 8;
  const float*          wf = w1f  + (h0 + l15) * 256 + lq * 8;

  // prologue: load+pack t=0,1 (pf = 8 uint2 = 16 VGPR)
  uint2 pf[8];
#pragma unroll
  for (int tl = 0; tl < 2; ++tl)
#pragma unroll
    for (int j = 0; j < 4; ++j) {
      const float4 v = *reinterpret_cast<const float4*>(xrow + tl * 256 + (sc + j * 16) * 4);
      pf[tl * 4 + j] = make_uint2(bfpack(v.x, v.y), bfpack(v.z, v.w));
    }

#pragma unroll 1
  for (int tt = 0; tt < 10; tt += 2) {
    const int par = (tt >> 1) & 1;
    // ---- A: write pf -> xt[par][tl]; issue+pack loads for tt+2,tt+3 (full-iter cover).
    //      xt[par] last read at iter-2; the iter-1 barrier separates -> safe (R19 proof).
#pragma unroll
    for (int tl = 0; tl < 2; ++tl)
#pragma unroll
      for (int j = 0; j < 4; ++j)
        *reinterpret_cast<uint2*>(
            &xt[par][tl][j >> 1][sr][(sc + (j & 1) * 16) * 4]) = pf[tl * 4 + j];
    {
      const int t2 = (tt < 8) ? tt + 2 : 8;   // tail: harmless re-read of t=8,9
#pragma unroll
      for (int tl = 0; tl < 2; ++tl)
#pragma unroll
        for (int j = 0; j < 4; ++j) {
          const float4 v = *reinterpret_cast<const float4*>(
              xrow + (t2 + tl) * 256 + (sc + j * 16) * 4);
          pf[tl * 4 + j] = make_uint2(bfpack(v.x, v.y), bfpack(v.z, v.w));
        }
    }
    __syncthreads();   // the ONLY barrier per 2t-iteration

    // ======== two cp-passes; kk body: 4 a-loads + 2 W1-loads + 8 MFMA ========
#pragma unroll 1
    for (int cp = 0; cp < 2; ++cp) {
      const int cbase = cp * 2;
      f32x4 acc[2][2][2];   // [tl][rt][c] = 32 regs
#pragma unroll
      for (int tl = 0; tl < 2; ++tl)
#pragma unroll
        for (int rt = 0; rt < 2; ++rt)
#pragma unroll
          for (int c = 0; c < 2; ++c) {
            f32x4 cc = { b1l[cbase + c], b1l[cbase + c], b1l[cbase + c], b1l[cbase + c] };
            acc[tl][rt][c] = cc;
          }

#pragma unroll
      for (int kk = 0; kk < 8; ++kk) {
        short8 a[2][2], bfr[2];   // a[tl][rt]
#pragma unroll
        for (int tl = 0; tl < 2; ++tl)
#pragma unroll
          for (int rt = 0; rt < 2; ++rt)
            a[tl][rt] = *reinterpret_cast<const short8*>(
                &xt[par][tl][kk >> 2][rt * 16 + l15][(kk & 3) * 32 + lq * 8]);
#pragma unroll
        for (int c = 0; c < 2; ++c) {
          if constexpr (USE_WS)
            bfr[c] = *reinterpret_cast<const short8*>(wb + (cbase + c) * 4096 + kk * 32);
          else
            bfr[c] = cvt_frag(wf + (cbase + c) * 4096 + kk * 32);
        }
#pragma unroll
        for (int tl = 0; tl < 2; ++tl)
#pragma unroll
          for (int rt = 0; rt < 2; ++rt)
#pragma unroll
            for (int c = 0; c < 2; ++c)
              acc[tl][rt][c] = __builtin_amdgcn_mfma_f32_16x16x32_bf16(
                  a[tl][rt], bfr[c], acc[tl][rt][c], 0, 0, 0);
      }

      // LIF for this cp: per rt, one plane RMW covers t and t+1
#pragma unroll
      for (int rt = 0; rt < 2; ++rt) {
        float pr0[4] = {0.f, 0.f, 0.f, 0.f};
        float pr1[4] = {0.f, 0.f, 0.f, 0.f};
#pragma unroll
        for (int c = 0; c < 2; ++c) {
          const int p = rt * 4 + cbase + c;
          f32x4* slot = reinterpret_cast<f32x4*>(&mem_lds[p][tid][0]);
          f32x4 mv = *slot;
          lif4(mv, acc[0][rt][c], w2l[cbase + c], pr0);   // t
          lif4(mv, acc[1][rt][c], w2l[cbase + c], pr1);   // t+1
          *slot = mv;
        }
#pragma unroll
        for (int e = 0; e < 4; ++e) {
          float v0 = pr0[e];
          v0 += __shfl_xor(v0, 1); v0 += __shfl_xor(v0, 2);
          v0 += __shfl_xor(v0, 4); v0 += __shfl_xor(v0, 8);
          float v1 = pr1[e];
          v1 += __shfl_xor(v1, 1); v1 += __shfl_xor(v1, 2);
          v1 += __shfl_xor(v1, 4); v1 += __shfl_xor(v1, 8);
          if (l15 == 0) {
            const int row = rt * 16 + lq * 4 + e;
            if (cp == 0) {
              cur2_lds[tt][row][wave] = v0;
              cur2_lds[tt + 1][row][wave] = v1;
            } else {
              cur2_lds[tt][row][wave] += v0;
              cur2_lds[tt + 1][row][wave] += v1;
            }
          }
        }
      }
    }
    // no trailing barrier: cur2_lds[tt,tt+1] not read until after the final barrier
  }

  __syncthreads();   // final: all cur2 partials visible

  // ---- deferred LIF2: 10-step chain, once, on 32 threads ----
  if (tid < 32) {
    const float bias2 = b2[0];
    float mem2 = 0.f, spksum = 0.f;
#pragma unroll
    for (int t = 0; t < 10; ++t) {
      float c2 = bias2;
#pragma unroll
      for (int w = 0; w < 8; ++w) c2 += cur2_lds[t][tid][w];
      float m   = fmaf(mem2, 0.9f, c2);
      float spk = fast_sigmoid(fmaf(m, 10.f, -10.f));
      mem2   = m - spk;
      spksum += spk;
    }
    out[b0 + tid] = fast_sigmoid(spksum * 0.1f);   // FLOAT32 output
  }
}

extern "C" void kernel_launch(void* const* d_in, const int* in_sizes, int n_in,
                              void* d_out, int out_size, void* d_ws, size_t ws_size,
                              hipStream_t stream) {
  const float* x  = (const float*)d_in[0];
  const float* W1 = (const float*)d_in[1];
  const float* b1 = (const float*)d_in[2];
  const float* W2 = (const float*)d_in[3];
  const float* b2 = (const float*)d_in[4];
  float* out = (float*)d_out;
  (void)in_sizes; (void)n_in;

  const int grid = out_size / 32;   // out_size == B == 32768 -> 1024 blocks

  if (ws_size >= 512 * 256 * sizeof(unsigned short)) {
    unsigned short* w1bf = (unsigned short*)d_ws;   // 256 KB
    w1_to_bf16<<<128, 256, 0, stream>>>(W1, w1bf);
    snn_main<true><<<grid, 512, 0, stream>>>(x, w1bf, W1, b1, W2, b2, out);
  } else {
    snn_main<false><<<grid, 512, 0, stream>>>(x, nullptr, W1, b1, W2, b2, out);
  }
}

// Round 21
// 176.874 us; speedup vs baseline: 1.6824x; 1.6824x over previous
//
#include <hip/hip_runtime.h>
#include <hip/hip_bf16.h>

// FraudSNN fused kernel: GEMM (bf16 MFMA) + LIF recurrence, T=10, F=256, H=512.
// R21: R19 (177.6us; 1 barrier/t, deferred LIF2, parity-dbuf xt, spill-free) plus:
//  - s_setprio(1) around the MFMA kk loop (waves drift phases w/ 1 bar/t -> scheduler
//    favors MFMA-phase waves; T5)
//  - mem1 planes 6,7 in registers (live ~124 <= 128 budget; -4 LDS RMW/t/thread)
// 2-t fusion abandoned: R15/R18/R20 all spilled or fragmented (reg envelope too small).

typedef short short8 __attribute__((ext_vector_type(8)));
typedef float f32x4 __attribute__((ext_vector_type(4)));

__device__ __forceinline__ unsigned short bfbits(float f) {
  union { __hip_bfloat16 h; unsigned short u; } c;
  c.h = __float2bfloat16(f);   // hardware RNE
  return c.u;
}

__device__ __forceinline__ unsigned int bfpack(float a, float b) {
  return (unsigned int)bfbits(a) | ((unsigned int)bfbits(b) << 16);
}

__device__ __forceinline__ float fast_sigmoid(float z) {
  float e = __expf(-z);
  return __builtin_amdgcn_rcpf(1.0f + e);
}

__device__ __forceinline__ void lif4(f32x4& mv, const f32x4 av, float w2c, float pr[4]) {
#pragma unroll
  for (int e = 0; e < 4; ++e) {
    float m   = fmaf(mv[e], 0.9f, av[e]);     // beta*mem + cur1
    float spk = fast_sigmoid(fmaf(m, 10.f, -10.f));
    mv[e] = m - spk;
    pr[e] = fmaf(spk, w2c, pr[e]);
  }
}

__global__ void w1_to_bf16(const float* __restrict__ w1, unsigned short* __restrict__ o) {
  int i = blockIdx.x * 256 + threadIdx.x;      // 32768 float4s
  float4 v = reinterpret_cast<const float4*>(w1)[i];
  reinterpret_cast<uint2*>(o)[i] = make_uint2(bfpack(v.x, v.y), bfpack(v.z, v.w));
}

__device__ __forceinline__ short8 cvt_frag(const float* p) {
  const float4 v0 = *reinterpret_cast<const float4*>(p);
  const float4 v1 = *reinterpret_cast<const float4*>(p + 4);
  union { unsigned int u[4]; short8 s; } cv;
  cv.u[0] = bfpack(v0.x, v0.y);
  cv.u[1] = bfpack(v0.z, v0.w);
  cv.u[2] = bfpack(v1.x, v1.y);
  cv.u[3] = bfpack(v1.z, v1.w);
  return cv.s;
}

// 512 threads = 8 waves. Block: 32 batch rows; wave w owns 32 rows x h in [w*64, w*64+64).
template <bool USE_WS>
__global__
__attribute__((amdgpu_flat_work_group_size(512, 512)))
void snn_main(const float* __restrict__ x,
              const unsigned short* __restrict__ w1bf,  // bf16 W1 (if USE_WS)
              const float* __restrict__ w1f,            // fp32 W1 (fallback)
              const float* __restrict__ b1,
              const float* __restrict__ w2,
              const float* __restrict__ b2,
              float* __restrict__ out)
{
  __shared__ __align__(16) float mem_lds[6][512][4];          // 49,152 B, 0-conflict slots
  __shared__ __align__(16) unsigned short xt[2][2][32][132];  // [par][half][row][col] 33,792 B
  __shared__ float cur2_lds[10][32][9];                       // [t][row][wave] 11,520 B

  const int tid  = threadIdx.x;
  const int lane = tid & 63;
  const int wave = tid >> 6;          // 0..7
  const int l15  = lane & 15;
  const int lq   = lane >> 4;         // 0..3
  const long b0  = (long)blockIdx.x * 32;
  const int h0   = wave * 64;         // 4 col-tiles of 16

  float w2l[4], b1l[4];
#pragma unroll
  for (int ct = 0; ct < 4; ++ct) {
    int h = h0 + ct * 16 + l15;
    w2l[ct] = w2[h];
    b1l[ct] = b1[h];
  }

#pragma unroll
  for (int p = 0; p < 6; ++p) {
    f32x4 z = {0.f, 0.f, 0.f, 0.f};
    *reinterpret_cast<f32x4*>(&mem_lds[p][tid][0]) = z;
  }
  f32x4 m6 = {0.f, 0.f, 0.f, 0.f}, m7 = m6;   // planes 6,7 (rt1, ct2/ct3) in regs

  // staging: thread -> row sr (0..31), float4 col sc (0..15); 4 float4 per t
  const int sr = tid >> 4;
  const int sc = tid & 15;
  const float* xrow = x + (b0 + sr) * 2560;

  const unsigned short* wb = w1bf + (h0 + l15) * 256 + lq * 8;
  const float*          wf = w1f  + (h0 + l15) * 256 + lq * 8;

  // prologue: load+pack t=0 (pf = 4 uint2 = 8 VGPR)
  uint2 pf[4];
#pragma unroll
  for (int j = 0; j < 4; ++j) {
    const float4 v = *reinterpret_cast<const float4*>(xrow + (sc + j * 16) * 4);
    pf[j] = make_uint2(bfpack(v.x, v.y), bfpack(v.z, v.w));
  }

#pragma unroll 1
  for (int t = 0; t < 10; ++t) {
    const int par = t & 1;
    // ---- A: write pf(t) -> xt[par]; issue+pack loads for t+1 (full-phase cover).
    //      xt[par] was last read at compute(t-2); bar(t-1) separates -> safe. ----
#pragma unroll
    for (int j = 0; j < 4; ++j)
      *reinterpret_cast<uint2*>(
          &xt[par][j >> 1][sr][(sc + (j & 1) * 16) * 4]) = pf[j];
    {
      const int tn = (t < 9) ? t + 1 : 9;   // tail: harmless re-read
#pragma unroll
      for (int j = 0; j < 4; ++j) {
        const float4 v = *reinterpret_cast<const float4*>(
            xrow + tn * 256 + (sc + j * 16) * 4);
        pf[j] = make_uint2(bfpack(v.x, v.y), bfpack(v.z, v.w));
      }
    }
    // hoist kk=0 W1 fragments above the barrier (L2 latency covered by barrier wait)
    short8 bfr0[4];
#pragma unroll
    for (int c = 0; c < 4; ++c) {
      if constexpr (USE_WS) bfr0[c] = *reinterpret_cast<const short8*>(wb + c * 4096);
      else                  bfr0[c] = cvt_frag(wf + c * 4096);
    }
    __syncthreads();   // the ONLY per-t barrier: xt[par] visible

    // ---- single-pass GEMM: acc[2][4] = 32 regs, 8 MFMA per kk ----
    f32x4 acc[2][4];
#pragma unroll
    for (int rt = 0; rt < 2; ++rt)
#pragma unroll
      for (int c = 0; c < 4; ++c) {
        f32x4 cc = { b1l[c], b1l[c], b1l[c], b1l[c] };
        acc[rt][c] = cc;
      }

    __builtin_amdgcn_s_setprio(1);
#pragma unroll
    for (int kk = 0; kk < 8; ++kk) {
      short8 a[2], bfr[4];
#pragma unroll
      for (int rt = 0; rt < 2; ++rt)
        a[rt] = *reinterpret_cast<const short8*>(
            &xt[par][kk >> 2][rt * 16 + l15][(kk & 3) * 32 + lq * 8]);
      if (kk == 0) {
#pragma unroll
        for (int c = 0; c < 4; ++c) bfr[c] = bfr0[c];
      } else {
#pragma unroll
        for (int c = 0; c < 4; ++c) {
          if constexpr (USE_WS)
            bfr[c] = *reinterpret_cast<const short8*>(wb + c * 4096 + kk * 32);
          else
            bfr[c] = cvt_frag(wf + c * 4096 + kk * 32);
        }
      }
#pragma unroll
      for (int rt = 0; rt < 2; ++rt)
#pragma unroll
        for (int c = 0; c < 4; ++c)
          acc[rt][c] = __builtin_amdgcn_mfma_f32_16x16x32_bf16(a[rt], bfr[c], acc[rt][c], 0, 0, 0);
    }
    __builtin_amdgcn_s_setprio(0);

    // ---- LIF1 + partial W2 dot; planes 0..5 in LDS, 6..7 in regs ----
#pragma unroll
    for (int rt = 0; rt < 2; ++rt) {
      float pr[4] = {0.f, 0.f, 0.f, 0.f};
#pragma unroll
      for (int c = 0; c < 4; ++c) {
        const int p = rt * 4 + c;
        if (p < 6) {
          f32x4* slot = reinterpret_cast<f32x4*>(&mem_lds[p][tid][0]);
          f32x4 mv = *slot;
          lif4(mv, acc[rt][c], w2l[c], pr);
          *slot = mv;
        } else if (p == 6) {
          lif4(m6, acc[rt][c], w2l[c], pr);
        } else {
          lif4(m7, acc[rt][c], w2l[c], pr);
        }
      }
#pragma unroll
      for (int e = 0; e < 4; ++e) {
        float v = pr[e];
        v += __shfl_xor(v, 1); v += __shfl_xor(v, 2);
        v += __shfl_xor(v, 4); v += __shfl_xor(v, 8);
        if (l15 == 0) cur2_lds[t][rt * 16 + lq * 4 + e][wave] = v;
      }
    }
    // no second barrier: cur2_lds[t] is not read until after the final barrier
  }

  __syncthreads();   // final: all cur2 partials visible

  // ---- deferred LIF2: 10-step chain, once, on 32 threads ----
  if (tid < 32) {
    const float bias2 = b2[0];
    float mem2 = 0.f, spksum = 0.f;
#pragma unroll
    for (int t = 0; t < 10; ++t) {
      float c2 = bias2;
#pragma unroll
      for (int w = 0; w < 8; ++w) c2 += cur2_lds[t][tid][w];
      float m   = fmaf(mem2, 0.9f, c2);
      float spk = fast_sigmoid(fmaf(m, 10.f, -10.f));
      mem2   = m - spk;
      spksum += spk;
    }
    out[b0 + tid] = fast_sigmoid(spksum * 0.1f);   // FLOAT32 output
  }
}

extern "C" void kernel_launch(void* const* d_in, const int* in_sizes, int n_in,
                              void* d_out, int out_size, void* d_ws, size_t ws_size,
                              hipStream_t stream) {
  const float* x  = (const float*)d_in[0];
  const float* W1 = (const float*)d_in[1];
  const float* b1 = (const float*)d_in[2];
  const float* W2 = (const float*)d_in[3];
  const float* b2 = (const float*)d_in[4];
  float* out = (float*)d_out;
  (void)in_sizes; (void)n_in;

  const int grid = out_size / 32;   // out_size == B == 32768 -> 1024 blocks

  if (ws_size >= 512 * 256 * sizeof(unsigned short)) {
    unsigned short* w1bf = (unsigned short*)d_ws;   // 256 KB
    w1_to_bf16<<<128, 256, 0, stream>>>(W1, w1bf);
    snn_main<true><<<grid, 512, 0, stream>>>(x, w1bf, W1, b1, W2, b2, out);
  } else {
    snn_main<false><<<grid, 512, 0, stream>>>(x, nullptr, W1, b1, W2, b2, out);
  }
}

// Round 23
// 174.767 us; speedup vs baseline: 1.7027x; 1.0121x over previous
//
#include <hip/hip_runtime.h>
#include <hip/hip_bf16.h>

// FraudSNN fused kernel: GEMM (bf16 MFMA) + LIF recurrence, T=10, F=256, H=512.
// R23: R22's W1-LDS-cache with the staging bugs fixed:
//  - w1s[512][72]: stride 144 B (16B-aligned for short8 reads); 36 dw = 4 mod 32
//    -> 2 lanes/bank on the l15 axis = free tier (m136), same class as xt.
//  - copy covers ALL 64 shorts/row (8 x uint4); R22 copied 4-short pieces at
//    8-short stride, leaving half the row poisoned -> NaN.
// Frame = R21 (176.9us): 1 barrier/t, deferred LIF2, parity-dbuf xt, planes 5-7 in
// regs, kk=2 hoist, setprio. kk 0-1 W1 now from LDS: per-t W1-L2 traffic -25%.
// LDS exactly 160,000 B; live ~124 regs.

typedef short short8 __attribute__((ext_vector_type(8)));
typedef float f32x4 __attribute__((ext_vector_type(4)));

__device__ __forceinline__ unsigned short bfbits(float f) {
  union { __hip_bfloat16 h; unsigned short u; } c;
  c.h = __float2bfloat16(f);   // hardware RNE
  return c.u;
}

__device__ __forceinline__ unsigned int bfpack(float a, float b) {
  return (unsigned int)bfbits(a) | ((unsigned int)bfbits(b) << 16);
}

__device__ __forceinline__ float fast_sigmoid(float z) {
  float e = __expf(-z);
  return __builtin_amdgcn_rcpf(1.0f + e);
}

__device__ __forceinline__ void lif4(f32x4& mv, const f32x4 av, float w2c, float pr[4]) {
#pragma unroll
  for (int e = 0; e < 4; ++e) {
    float m   = fmaf(mv[e], 0.9f, av[e]);     // beta*mem + cur1
    float spk = fast_sigmoid(fmaf(m, 10.f, -10.f));
    mv[e] = m - spk;
    pr[e] = fmaf(spk, w2c, pr[e]);
  }
}

__global__ void w1_to_bf16(const float* __restrict__ w1, unsigned short* __restrict__ o) {
  int i = blockIdx.x * 256 + threadIdx.x;      // 32768 float4s
  float4 v = reinterpret_cast<const float4*>(w1)[i];
  reinterpret_cast<uint2*>(o)[i] = make_uint2(bfpack(v.x, v.y), bfpack(v.z, v.w));
}

__device__ __forceinline__ short8 cvt_frag(const float* p) {
  const float4 v0 = *reinterpret_cast<const float4*>(p);
  const float4 v1 = *reinterpret_cast<const float4*>(p + 4);
  union { unsigned int u[4]; short8 s; } cv;
  cv.u[0] = bfpack(v0.x, v0.y);
  cv.u[1] = bfpack(v0.z, v0.w);
  cv.u[2] = bfpack(v1.x, v1.y);
  cv.u[3] = bfpack(v1.z, v1.w);
  return cv.s;
}

// 512 threads = 8 waves. Block: 32 batch rows; wave w owns 32 rows x h in [w*64, w*64+64).
template <bool USE_WS>
__global__
__attribute__((amdgpu_flat_work_group_size(512, 512)))
void snn_main(const float* __restrict__ x,
              const unsigned short* __restrict__ w1bf,  // bf16 W1 (if USE_WS)
              const float* __restrict__ w1f,            // fp32 W1 (fallback)
              const float* __restrict__ b1,
              const float* __restrict__ w2,
              const float* __restrict__ b2,
              float* __restrict__ out)
{
  __shared__ __align__(16) float mem_lds[5][512][4];          // 40,960 B, 0-conflict slots
  __shared__ __align__(16) unsigned short xt[2][2][32][132];  // [par][half][row][col] 33,792 B
  __shared__ __align__(16) unsigned short w1s[512][72];       // W1 kk0-1 slice, 73,728 B
  __shared__ float cur2_lds[10][32][9];                       // [t][row][wave] 11,520 B
                                                              // total 160,000 B

  const int tid  = threadIdx.x;
  const int lane = tid & 63;
  const int wave = tid >> 6;          // 0..7
  const int l15  = lane & 15;
  const int lq   = lane >> 4;         // 0..3
  const long b0  = (long)blockIdx.x * 32;
  const int h0   = wave * 64;         // 4 col-tiles of 16

  float w2l[4], b1l[4];
#pragma unroll
  for (int ct = 0; ct < 4; ++ct) {
    int h = h0 + ct * 16 + l15;
    w2l[ct] = w2[h];
    b1l[ct] = b1[h];
  }

#pragma unroll
  for (int p = 0; p < 5; ++p) {
    f32x4 z = {0.f, 0.f, 0.f, 0.f};
    *reinterpret_cast<f32x4*>(&mem_lds[p][tid][0]) = z;
  }
  f32x4 m5 = {0.f, 0.f, 0.f, 0.f}, m6 = m5, m7 = m5;  // planes 5,6,7 (rt1 ct1/2/3)

  // ---- stage W1 kk0-1 slice -> LDS, once per block (fenced by t=0's barrier) ----
  // thread tid stages h-row tid: 64 bf16 = 128 B -> w1s[tid][0..63] (8 x uint4)
  if constexpr (USE_WS) {
    const unsigned short* src = w1bf + tid * 256;
#pragma unroll
    for (int j = 0; j < 8; ++j)
      *reinterpret_cast<uint4*>(&w1s[tid][j * 8]) =
          *reinterpret_cast<const uint4*>(src + j * 8);
  } else {
    const float* src = w1f + tid * 256;
#pragma unroll
    for (int j = 0; j < 8; ++j) {
      short8 s = cvt_frag(src + j * 8);
      *reinterpret_cast<short8*>(&w1s[tid][j * 8]) = s;
    }
  }

  // staging: thread -> row sr (0..31), float4 col sc (0..15); 4 float4 per t
  const int sr = tid >> 4;
  const int sc = tid & 15;
  const float* xrow = x + (b0 + sr) * 2560;

  const unsigned short* wb = w1bf + (h0 + l15) * 256 + lq * 8;
  const float*          wf = w1f  + (h0 + l15) * 256 + lq * 8;

  // prologue: load+pack t=0 (pf = 4 uint2 = 8 VGPR)
  uint2 pf[4];
#pragma unroll
  for (int j = 0; j < 4; ++j) {
    const float4 v = *reinterpret_cast<const float4*>(xrow + (sc + j * 16) * 4);
    pf[j] = make_uint2(bfpack(v.x, v.y), bfpack(v.z, v.w));
  }

#pragma unroll 1
  for (int t = 0; t < 10; ++t) {
    const int par = t & 1;
    // ---- A: write pf(t) -> xt[par]; issue+pack loads for t+1 (full-phase cover).
    //      xt[par] was last read at compute(t-2); bar(t-1) separates -> safe. ----
#pragma unroll
    for (int j = 0; j < 4; ++j)
      *reinterpret_cast<uint2*>(
          &xt[par][j >> 1][sr][(sc + (j & 1) * 16) * 4]) = pf[j];
    {
      const int tn = (t < 9) ? t + 1 : 9;   // tail: harmless re-read
#pragma unroll
      for (int j = 0; j < 4; ++j) {
        const float4 v = *reinterpret_cast<const float4*>(
            xrow + tn * 256 + (sc + j * 16) * 4);
        pf[j] = make_uint2(bfpack(v.x, v.y), bfpack(v.z, v.w));
      }
    }
    // hoist kk=2 W1 fragments above the barrier (first L2 kk; latency under barrier)
    short8 bfr0[4];
#pragma unroll
    for (int c = 0; c < 4; ++c) {
      if constexpr (USE_WS) bfr0[c] = *reinterpret_cast<const short8*>(wb + c * 4096 + 2 * 32);
      else                  bfr0[c] = cvt_frag(wf + c * 4096 + 2 * 32);
    }
    __syncthreads();   // the ONLY per-t barrier: xt[par] (and, at t=0, w1s) visible

    // ---- single-pass GEMM: acc[2][4] = 32 regs, 8 MFMA per kk ----
    f32x4 acc[2][4];
#pragma unroll
    for (int rt = 0; rt < 2; ++rt)
#pragma unroll
      for (int c = 0; c < 4; ++c) {
        f32x4 cc = { b1l[c], b1l[c], b1l[c], b1l[c] };
        acc[rt][c] = cc;
      }

    __builtin_amdgcn_s_setprio(1);
#pragma unroll
    for (int kk = 0; kk < 8; ++kk) {
      short8 a[2], bfr[4];
#pragma unroll
      for (int rt = 0; rt < 2; ++rt)
        a[rt] = *reinterpret_cast<const short8*>(
            &xt[par][kk >> 2][rt * 16 + l15][(kk & 3) * 32 + lq * 8]);
      if (kk < 2) {
        // W1 from the LDS-cached slice (144B stride: 16B-aligned, 2-lane/bank free)
#pragma unroll
        for (int c = 0; c < 4; ++c)
          bfr[c] = *reinterpret_cast<const short8*>(
              &w1s[h0 + c * 16 + l15][kk * 32 + lq * 8]);
      } else if (kk == 2) {
#pragma unroll
        for (int c = 0; c < 4; ++c) bfr[c] = bfr0[c];
      } else {
#pragma unroll
        for (int c = 0; c < 4; ++c) {
          if constexpr (USE_WS)
            bfr[c] = *reinterpret_cast<const short8*>(wb + c * 4096 + kk * 32);
          else
            bfr[c] = cvt_frag(wf + c * 4096 + kk * 32);
        }
      }
#pragma unroll
      for (int rt = 0; rt < 2; ++rt)
#pragma unroll
        for (int c = 0; c < 4; ++c)
          acc[rt][c] = __builtin_amdgcn_mfma_f32_16x16x32_bf16(a[rt], bfr[c], acc[rt][c], 0, 0, 0);
    }
    __builtin_amdgcn_s_setprio(0);

    // ---- LIF1 + partial W2 dot; planes 0..4 in LDS, 5..7 in regs ----
#pragma unroll
    for (int rt = 0; rt < 2; ++rt) {
      float pr[4] = {0.f, 0.f, 0.f, 0.f};
#pragma unroll
      for (int c = 0; c < 4; ++c) {
        const int p = rt * 4 + c;
        if (p < 5) {
          f32x4* slot = reinterpret_cast<f32x4*>(&mem_lds[p][tid][0]);
          f32x4 mv = *slot;
          lif4(mv, acc[rt][c], w2l[c], pr);
          *slot = mv;
        } else if (p == 5) {
          lif4(m5, acc[rt][c], w2l[c], pr);
        } else if (p == 6) {
          lif4(m6, acc[rt][c], w2l[c], pr);
        } else {
          lif4(m7, acc[rt][c], w2l[c], pr);
        }
      }
#pragma unroll
      for (int e = 0; e < 4; ++e) {
        float v = pr[e];
        v += __shfl_xor(v, 1); v += __shfl_xor(v, 2);
        v += __shfl_xor(v, 4); v += __shfl_xor(v, 8);
        if (l15 == 0) cur2_lds[t][rt * 16 + lq * 4 + e][wave] = v;
      }
    }
    // no second barrier: cur2_lds[t] is not read until after the final barrier
  }

  __syncthreads();   // final: all cur2 partials visible

  // ---- deferred LIF2: 10-step chain, once, on 32 threads ----
  if (tid < 32) {
    const float bias2 = b2[0];
    float mem2 = 0.f, spksum = 0.f;
#pragma unroll
    for (int t = 0; t < 10; ++t) {
      float c2 = bias2;
#pragma unroll
      for (int w = 0; w < 8; ++w) c2 += cur2_lds[t][tid][w];
      float m   = fmaf(mem2, 0.9f, c2);
      float spk = fast_sigmoid(fmaf(m, 10.f, -10.f));
      mem2   = m - spk;
      spksum += spk;
    }
    out[b0 + tid] = fast_sigmoid(spksum * 0.1f);   // FLOAT32 output
  }
}

extern "C" void kernel_launch(void* const* d_in, const int* in_sizes, int n_in,
                              void* d_out, int out_size, void* d_ws, size_t ws_size,
                              hipStream_t stream) {
  const float* x  = (const float*)d_in[0];
  const float* W1 = (const float*)d_in[1];
  const float* b1 = (const float*)d_in[2];
  const float* W2 = (const float*)d_in[3];
  const float* b2 = (const float*)d_in[4];
  float* out = (float*)d_out;
  (void)in_sizes; (void)n_in;

  const int grid = out_size / 32;   // out_size == B == 32768 -> 1024 blocks

  if (ws_size >= 512 * 256 * sizeof(unsigned short)) {
    unsigned short* w1bf = (unsigned short*)d_ws;   // 256 KB
    w1_to_bf16<<<128, 256, 0, stream>>>(W1, w1bf);
    snn_main<true><<<grid, 512, 0, stream>>>(x, w1bf, W1, b1, W2, b2, out);
  } else {
    snn_main<false><<<grid, 512, 0, stream>>>(x, nullptr, W1, b1, W2, b2, out);
  }
}